// Round 1
// baseline (760.359 us; speedup 1.0000x reference)
//
#include <hip/hip_runtime.h>
#include <hip/hip_bf16.h>
#include <math.h>

#define N_NODES 20000
#define N_EDGES 640000
#define F_IN 128
#define HID 64
#define HEADS 4
#define HC 256      // HEADS*HID
#define OUT_DIM 10
#define NUM_GRAPHS 128
#define NEG_SLOPE 0.2f
#define BN_EPS 1e-5f

// ---------------- utility kernels ----------------

__global__ void fill_i32(int* p, int n, int val) {
    int tid = blockIdx.x * blockDim.x + threadIdx.x;
    if (tid < n) p[tid] = val;
}

__global__ void fill_f32(float* p, int n, float val) {
    int tid = blockIdx.x * blockDim.x + threadIdx.x;
    if (tid < n) p[tid] = val;
}

__global__ void copy_i32(int* dst, const int* src, int n) {
    int tid = blockIdx.x * blockDim.x + threadIdx.x;
    if (tid < n) dst[tid] = src[tid];
}

// ---------------- CSR build ----------------

// count in-degree (deg pre-initialized to 1 for the self loop)
__global__ void count_deg(const int* __restrict__ ei_dst, int* deg, int E) {
    int tid = blockIdx.x * blockDim.x + threadIdx.x;
    if (tid < E) atomicAdd(&deg[ei_dst[tid]], 1);
}

// single-block exclusive scan over n elements -> rowptr[0..n]
__global__ void scan_deg(const int* __restrict__ deg, int* __restrict__ rowptr, int n) {
    __shared__ int sdata[1024];
    __shared__ int carry;
    if (threadIdx.x == 0) { carry = 0; rowptr[0] = 0; }
    __syncthreads();
    for (int base = 0; base < n; base += 1024) {
        int i = base + threadIdx.x;
        int v = (i < n) ? deg[i] : 0;
        sdata[threadIdx.x] = v;
        __syncthreads();
        for (int off = 1; off < 1024; off <<= 1) {
            int t = (threadIdx.x >= off) ? sdata[threadIdx.x - off] : 0;
            __syncthreads();
            sdata[threadIdx.x] += t;
            __syncthreads();
        }
        int inc = sdata[threadIdx.x] + carry;
        if (i < n) rowptr[i + 1] = inc;
        __syncthreads();
        if (threadIdx.x == 1023) carry = inc;
        __syncthreads();
    }
}

// scatter edges (and self-loops) into CSR slots
__global__ void fill_csr(const int* __restrict__ ei, int* cursor, int* esrc, int E, int n) {
    int tid = blockIdx.x * blockDim.x + threadIdx.x;
    if (tid < E) {
        int src = ei[tid];
        int dst = ei[E + tid];
        int pos = atomicAdd(&cursor[dst], 1);
        esrc[pos] = src;
    } else if (tid < E + n) {
        int node = tid - E;
        int pos = atomicAdd(&cursor[node], 1);
        esrc[pos] = node;
    }
}

// ---------------- GEMM: C[M,256] = A[M,K] @ B[K,256] ----------------

__global__ __launch_bounds__(256) void gemm_f32(
        const float* __restrict__ A, const float* __restrict__ B,
        float* __restrict__ C, int M, int K) {
    const int NC = HC;  // 256 columns
    __shared__ float As[32][68];   // [BK][BM+4]
    __shared__ float Bs[32][64];
    int tid = threadIdx.x;
    int row0 = blockIdx.x * 64;
    int col0 = blockIdx.y * 64;
    int tx = tid & 15, ty = tid >> 4;
    float acc[4][4] = {};
    for (int k0 = 0; k0 < K; k0 += 32) {
        #pragma unroll
        for (int i = 0; i < 8; i++) {
            int idx = tid + i * 256;
            int m = idx >> 5, kk = idx & 31;
            int gr = row0 + m;
            As[kk][m] = (gr < M) ? A[(size_t)gr * K + k0 + kk] : 0.f;
        }
        #pragma unroll
        for (int i = 0; i < 8; i++) {
            int idx = tid + i * 256;
            int kk = idx >> 6, c = idx & 63;
            Bs[kk][c] = B[(size_t)(k0 + kk) * NC + col0 + c];
        }
        __syncthreads();
        #pragma unroll
        for (int kk = 0; kk < 32; ++kk) {
            float a0 = As[kk][ty * 4 + 0], a1 = As[kk][ty * 4 + 1];
            float a2 = As[kk][ty * 4 + 2], a3 = As[kk][ty * 4 + 3];
            float b0 = Bs[kk][tx * 4 + 0], b1 = Bs[kk][tx * 4 + 1];
            float b2 = Bs[kk][tx * 4 + 2], b3 = Bs[kk][tx * 4 + 3];
            acc[0][0] += a0 * b0; acc[0][1] += a0 * b1; acc[0][2] += a0 * b2; acc[0][3] += a0 * b3;
            acc[1][0] += a1 * b0; acc[1][1] += a1 * b1; acc[1][2] += a1 * b2; acc[1][3] += a1 * b3;
            acc[2][0] += a2 * b0; acc[2][1] += a2 * b1; acc[2][2] += a2 * b2; acc[2][3] += a2 * b3;
            acc[3][0] += a3 * b0; acc[3][1] += a3 * b1; acc[3][2] += a3 * b2; acc[3][3] += a3 * b3;
        }
        __syncthreads();
    }
    #pragma unroll
    for (int i = 0; i < 4; i++) {
        int gr = row0 + ty * 4 + i;
        if (gr < M) {
            float4 v;
            v.x = acc[i][0]; v.y = acc[i][1]; v.z = acc[i][2]; v.w = acc[i][3];
            *reinterpret_cast<float4*>(C + (size_t)gr * NC + col0 + tx * 4) = v;
        }
    }
}

// ---------------- attention coefficients: as/ad [N,H] ----------------

__global__ void attn_coef(const float* __restrict__ hfeat,
                          const float* __restrict__ a_src, const float* __restrict__ a_dst,
                          float* __restrict__ asb, float* __restrict__ adb, int n) {
    int wave = blockIdx.x * (blockDim.x >> 6) + (threadIdx.x >> 6);
    int lane = threadIdx.x & 63;
    if (wave >= n) return;
    int h = lane >> 4;
    int c4 = (lane & 15) * 4;
    const float4 hv = *reinterpret_cast<const float4*>(hfeat + (size_t)wave * HC + h * HID + c4);
    const float4 sv = *reinterpret_cast<const float4*>(a_src + h * HID + c4);
    const float4 dv = *reinterpret_cast<const float4*>(a_dst + h * HID + c4);
    float s = hv.x * sv.x + hv.y * sv.y + hv.z * sv.z + hv.w * sv.w;
    float d = hv.x * dv.x + hv.y * dv.y + hv.z * dv.z + hv.w * dv.w;
    #pragma unroll
    for (int off = 8; off > 0; off >>= 1) {
        s += __shfl_xor(s, off);
        d += __shfl_xor(d, off);
    }
    if ((lane & 15) == 0) {
        asb[wave * HEADS + h] = s;
        adb[wave * HEADS + h] = d;
    }
}

// ---------------- GAT aggregation: wave per destination node ----------------

__device__ __forceinline__ float lrelu(float x) { return x > 0.f ? x : NEG_SLOPE * x; }

__global__ __launch_bounds__(256) void gat_aggregate(
        const float* __restrict__ hfeat,
        const float* __restrict__ asb, const float* __restrict__ adb,
        const int* __restrict__ rowptr, const int* __restrict__ esrc,
        const float* __restrict__ bias,  // [HC] or nullptr
        float* __restrict__ out) {       // [N,HC]
    int d = blockIdx.x * (blockDim.x >> 6) + (threadIdx.x >> 6);
    int lane = threadIdx.x & 63;
    if (d >= N_NODES) return;
    int start = rowptr[d], end = rowptr[d + 1];

    float adv0 = adb[d * HEADS + 0], adv1 = adb[d * HEADS + 1];
    float adv2 = adb[d * HEADS + 2], adv3 = adb[d * HEADS + 3];

    // pass 1: per-head max over edges
    float m0 = -1e30f, m1 = -1e30f, m2 = -1e30f, m3 = -1e30f;
    for (int j = start + lane; j < end; j += 64) {
        int s = esrc[j];
        const float4 av = *reinterpret_cast<const float4*>(asb + (size_t)s * HEADS);
        m0 = fmaxf(m0, lrelu(av.x + adv0));
        m1 = fmaxf(m1, lrelu(av.y + adv1));
        m2 = fmaxf(m2, lrelu(av.z + adv2));
        m3 = fmaxf(m3, lrelu(av.w + adv3));
    }
    #pragma unroll
    for (int off = 32; off > 0; off >>= 1) {
        m0 = fmaxf(m0, __shfl_xor(m0, off));
        m1 = fmaxf(m1, __shfl_xor(m1, off));
        m2 = fmaxf(m2, __shfl_xor(m2, off));
        m3 = fmaxf(m3, __shfl_xor(m3, off));
    }

    // pass 2: per-head sum of exp(e - m)
    float s0 = 0.f, s1 = 0.f, s2 = 0.f, s3 = 0.f;
    for (int j = start + lane; j < end; j += 64) {
        int s = esrc[j];
        const float4 av = *reinterpret_cast<const float4*>(asb + (size_t)s * HEADS);
        s0 += __expf(lrelu(av.x + adv0) - m0);
        s1 += __expf(lrelu(av.y + adv1) - m1);
        s2 += __expf(lrelu(av.z + adv2) - m2);
        s3 += __expf(lrelu(av.w + adv3) - m3);
    }
    #pragma unroll
    for (int off = 32; off > 0; off >>= 1) {
        s0 += __shfl_xor(s0, off);
        s1 += __shfl_xor(s1, off);
        s2 += __shfl_xor(s2, off);
        s3 += __shfl_xor(s3, off);
    }
    float r0 = 1.f / (s0 + 1e-16f), r1 = 1.f / (s1 + 1e-16f);
    float r2 = 1.f / (s2 + 1e-16f), r3 = 1.f / (s3 + 1e-16f);

    // pass 3: weighted accumulate of h[src]; lane covers cols [4*lane, 4*lane+4)
    int hsel = lane >> 4;
    float mh  = (hsel == 0) ? m0 : (hsel == 1) ? m1 : (hsel == 2) ? m2 : m3;
    float rdh = (hsel == 0) ? r0 : (hsel == 1) ? r1 : (hsel == 2) ? r2 : r3;
    float adh = (hsel == 0) ? adv0 : (hsel == 1) ? adv1 : (hsel == 2) ? adv2 : adv3;
    float ax = 0.f, ay = 0.f, az = 0.f, aw = 0.f;
    for (int j = start; j < end; ++j) {
        int s = esrc[j];
        float e = lrelu(asb[(size_t)s * HEADS + hsel] + adh);
        float alpha = __expf(e - mh) * rdh;
        const float4 v = *reinterpret_cast<const float4*>(hfeat + (size_t)s * HC + lane * 4);
        ax += alpha * v.x; ay += alpha * v.y; az += alpha * v.z; aw += alpha * v.w;
    }
    if (bias) {
        const float4 bv = *reinterpret_cast<const float4*>(bias + lane * 4);
        ax += bv.x; ay += bv.y; az += bv.z; aw += bv.w;
    }
    float4 o; o.x = ax; o.y = ay; o.z = az; o.w = aw;
    *reinterpret_cast<float4*>(out + (size_t)d * HC + lane * 4) = o;
}

// ---------------- BatchNorm ----------------

__global__ void bn_stats(const float* __restrict__ x, float* colsum, float* colsq, int n) {
    int col = threadIdx.x;  // 256 threads
    float s = 0.f, q = 0.f;
    for (int r = blockIdx.x; r < n; r += gridDim.x) {
        float v = x[(size_t)r * HC + col];
        s += v;
        q += v * v;
    }
    atomicAdd(&colsum[col], s);
    atomicAdd(&colsq[col], q);
}

__global__ void bn_finalize(const float* colsum, const float* colsq,
                            const float* __restrict__ g, const float* __restrict__ be,
                            float* scale, float* shift, int n) {
    int col = threadIdx.x;  // 256
    float mu = colsum[col] / (float)n;
    float var = colsq[col] / (float)n - mu * mu;
    float sc = g[col] * rsqrtf(var + BN_EPS);
    scale[col] = sc;
    shift[col] = be[col] - mu * sc;
}

__global__ void bn_apply_elu(const float* __restrict__ x,
                             const float* __restrict__ scale, const float* __restrict__ shift,
                             float* __restrict__ xs_out, float* __restrict__ act, int n) {
    int col = threadIdx.x;  // 256
    float sc = scale[col], sh = shift[col];
    for (int r = blockIdx.x; r < n; r += gridDim.x) {
        float v = x[(size_t)r * HC + col];
        float y = v * sc + sh;
        xs_out[(size_t)r * HC + col] = y;
        act[(size_t)r * HC + col] = y > 0.f ? y : __expf(y) - 1.f;
    }
}

// ---------------- layer-3 head mean, pool, final linear ----------------

__global__ void head_mean(const float* __restrict__ gatout, const float* __restrict__ b3,
                          float* __restrict__ xs2, int n) {
    int tid = blockIdx.x * blockDim.x + threadIdx.x;
    if (tid >= n * HID) return;
    int node = tid >> 6, c = tid & 63;
    const float* row = gatout + (size_t)node * HC;
    float v = 0.25f * (row[c] + row[HID + c] + row[2 * HID + c] + row[3 * HID + c]) + b3[c];
    xs2[tid] = v;
}

__global__ void pool_accum(const float* __restrict__ xs2, const int* __restrict__ batch,
                           float* pool, float* cnt, int n) {
    int tid = blockIdx.x * blockDim.x + threadIdx.x;
    if (tid >= n * HID) return;
    int node = tid >> 6, c = tid & 63;
    int g = batch[node];
    atomicAdd(&pool[g * HID + c], xs2[tid]);
    if (c == 0) atomicAdd(&cnt[g], 1.0f);
}

__global__ void pool_fin(const float* pool, const float* cnt, float* pooled_out) {
    int tid = blockIdx.x * blockDim.x + threadIdx.x;
    if (tid >= NUM_GRAPHS * HID) return;
    int g = tid >> 6;
    pooled_out[tid] = pool[tid] / fmaxf(cnt[g], 1.0f);
}

__global__ void final_linear(const float* __restrict__ pooled, const float* __restrict__ Wlin,
                             const float* __restrict__ blin, float* __restrict__ out) {
    int tid = blockIdx.x * blockDim.x + threadIdx.x;
    if (tid >= NUM_GRAPHS * OUT_DIM) return;
    int g = tid / OUT_DIM, o = tid % OUT_DIM;
    float s = blin[o];
    for (int c = 0; c < HID; ++c) s += pooled[g * HID + c] * Wlin[c * OUT_DIM + o];
    out[g * OUT_DIM + o] = s;
}

// ---------------- host side ----------------

extern "C" void kernel_launch(void* const* d_in, const int* in_sizes, int n_in,
                              void* d_out, int out_size, void* d_ws, size_t ws_size,
                              hipStream_t stream) {
    const float* x     = (const float*)d_in[0];
    const int*   ei    = (const int*)d_in[1];   // [2,E]
    const int*   batch = (const int*)d_in[2];
    const float* W1  = (const float*)d_in[3];
    const float* as1 = (const float*)d_in[4];
    const float* ad1 = (const float*)d_in[5];
    const float* b1  = (const float*)d_in[6];
    const float* g1  = (const float*)d_in[7];
    const float* be1 = (const float*)d_in[8];
    const float* W2  = (const float*)d_in[9];
    const float* as2 = (const float*)d_in[10];
    const float* ad2 = (const float*)d_in[11];
    const float* b2  = (const float*)d_in[12];
    const float* g2  = (const float*)d_in[13];
    const float* be2 = (const float*)d_in[14];
    const float* W3  = (const float*)d_in[15];
    const float* as3 = (const float*)d_in[16];
    const float* ad3 = (const float*)d_in[17];
    const float* b3  = (const float*)d_in[18];
    const float* Wlin = (const float*)d_in[19];
    const float* blin = (const float*)d_in[20];

    // output regions
    float* out_final = (float*)d_out;                 // [128,10]
    float* xs0 = out_final + NUM_GRAPHS * OUT_DIM;    // [N,256]
    float* xs1 = xs0 + (size_t)N_NODES * HC;          // [N,256]
    float* xs2 = xs1 + (size_t)N_NODES * HC;          // [N,64]
    float* pooled_out = xs2 + (size_t)N_NODES * HID;  // [128,64]

    // workspace carve
    char* p = (char*)d_ws;
    auto alloc = [&](size_t bytes) { char* r = p; p += (bytes + 255) & ~(size_t)255; return (void*)r; };
    float* hfeat  = (float*)alloc((size_t)N_NODES * HC * 4);
    float* gatB   = (float*)alloc((size_t)N_NODES * HC * 4);
    float* actC   = (float*)alloc((size_t)N_NODES * HC * 4);
    float* asb    = (float*)alloc((size_t)N_NODES * HEADS * 4);
    float* adb    = (float*)alloc((size_t)N_NODES * HEADS * 4);
    int*   deg    = (int*)alloc((size_t)N_NODES * 4);     // reused as cursor
    int*   rowptr = (int*)alloc((size_t)(N_NODES + 1) * 4);
    int*   esrc   = (int*)alloc((size_t)(N_EDGES + N_NODES) * 4);
    float* colsum = (float*)alloc(HC * 4);
    float* colsq  = (float*)alloc(HC * 4);
    float* scale  = (float*)alloc(HC * 4);
    float* shift  = (float*)alloc(HC * 4);
    float* pool   = (float*)alloc(NUM_GRAPHS * HID * 4);
    float* cnt    = (float*)alloc(NUM_GRAPHS * 4);

    const int ETOT = N_EDGES + N_NODES;

    // ---- CSR build (once, reused for all 3 layers) ----
    fill_i32<<<(N_NODES + 255) / 256, 256, 0, stream>>>(deg, N_NODES, 1);  // self-loop
    count_deg<<<(N_EDGES + 255) / 256, 256, 0, stream>>>(ei + N_EDGES, deg, N_EDGES);
    scan_deg<<<1, 1024, 0, stream>>>(deg, rowptr, N_NODES);
    copy_i32<<<(N_NODES + 255) / 256, 256, 0, stream>>>(deg, rowptr, N_NODES);  // deg -> cursor
    fill_csr<<<(ETOT + 255) / 256, 256, 0, stream>>>(ei, deg, esrc, N_EDGES, N_NODES);

    dim3 gemm_block(256);
    int wave_blocks = (N_NODES + 3) / 4;  // 4 waves per 256-thread block

    // ---- layer 1 ----
    {
        dim3 grid((N_NODES + 63) / 64, HC / 64);
        gemm_f32<<<grid, gemm_block, 0, stream>>>(x, W1, hfeat, N_NODES, F_IN);
        attn_coef<<<wave_blocks, 256, 0, stream>>>(hfeat, as1, ad1, asb, adb, N_NODES);
        gat_aggregate<<<wave_blocks, 256, 0, stream>>>(hfeat, asb, adb, rowptr, esrc, b1, gatB);
        fill_f32<<<2, 256, 0, stream>>>(colsum, HC, 0.f);
        fill_f32<<<2, 256, 0, stream>>>(colsq, HC, 0.f);
        bn_stats<<<512, 256, 0, stream>>>(gatB, colsum, colsq, N_NODES);
        bn_finalize<<<1, 256, 0, stream>>>(colsum, colsq, g1, be1, scale, shift, N_NODES);
        bn_apply_elu<<<2048, 256, 0, stream>>>(gatB, scale, shift, xs0, actC, N_NODES);
    }
    // ---- layer 2 ----
    {
        dim3 grid((N_NODES + 63) / 64, HC / 64);
        gemm_f32<<<grid, gemm_block, 0, stream>>>(actC, W2, hfeat, N_NODES, HC);
        attn_coef<<<wave_blocks, 256, 0, stream>>>(hfeat, as2, ad2, asb, adb, N_NODES);
        gat_aggregate<<<wave_blocks, 256, 0, stream>>>(hfeat, asb, adb, rowptr, esrc, b2, gatB);
        fill_f32<<<2, 256, 0, stream>>>(colsum, HC, 0.f);
        fill_f32<<<2, 256, 0, stream>>>(colsq, HC, 0.f);
        bn_stats<<<512, 256, 0, stream>>>(gatB, colsum, colsq, N_NODES);
        bn_finalize<<<1, 256, 0, stream>>>(colsum, colsq, g2, be2, scale, shift, N_NODES);
        bn_apply_elu<<<2048, 256, 0, stream>>>(gatB, scale, shift, xs1, actC, N_NODES);
    }
    // ---- layer 3 ----
    {
        dim3 grid((N_NODES + 63) / 64, HC / 64);
        gemm_f32<<<grid, gemm_block, 0, stream>>>(actC, W3, hfeat, N_NODES, HC);
        attn_coef<<<wave_blocks, 256, 0, stream>>>(hfeat, as3, ad3, asb, adb, N_NODES);
        gat_aggregate<<<wave_blocks, 256, 0, stream>>>(hfeat, asb, adb, rowptr, esrc, nullptr, gatB);
        head_mean<<<((N_NODES * HID) + 255) / 256, 256, 0, stream>>>(gatB, b3, xs2, N_NODES);
    }
    // ---- pool + final linear ----
    fill_f32<<<(NUM_GRAPHS * HID + 255) / 256, 256, 0, stream>>>(pool, NUM_GRAPHS * HID, 0.f);
    fill_f32<<<1, 128, 0, stream>>>(cnt, NUM_GRAPHS, 0.f);
    pool_accum<<<((N_NODES * HID) + 255) / 256, 256, 0, stream>>>(xs2, batch, pool, cnt, N_NODES);
    pool_fin<<<(NUM_GRAPHS * HID + 255) / 256, 256, 0, stream>>>(pool, cnt, pooled_out);
    final_linear<<<(NUM_GRAPHS * OUT_DIM + 255) / 256, 256, 0, stream>>>(pooled_out, Wlin, blin, out_final);
}

// Round 2
// 526.203 us; speedup vs baseline: 1.4450x; 1.4450x over previous
//
#include <hip/hip_runtime.h>
#include <hip/hip_bf16.h>
#include <math.h>

#define N_NODES 20000
#define N_EDGES 640000
#define F_IN 128
#define HID 64
#define HEADS 4
#define HC 256      // HEADS*HID
#define OUT_DIM 10
#define NUM_GRAPHS 128
#define NEG_SLOPE 0.2f
#define BN_EPS 1e-5f

typedef short bf16s;
using bf16x8 = __attribute__((ext_vector_type(8))) short;
using bf16x4 = __attribute__((ext_vector_type(4))) short;
using f32x4 = __attribute__((ext_vector_type(4))) float;

__device__ __forceinline__ float bs2f(short s) {
    unsigned int u = ((unsigned int)(unsigned short)s) << 16;
    return __builtin_bit_cast(float, u);
}
__device__ __forceinline__ short f2bs(float f) {
    unsigned int u = __builtin_bit_cast(unsigned int, f);
    unsigned int r = u + 0x7FFFu + ((u >> 16) & 1u);
    return (short)(r >> 16);
}

// ---------------- utility kernels ----------------

__global__ void fill_i32(int* p, int n, int val) {
    int tid = blockIdx.x * blockDim.x + threadIdx.x;
    if (tid < n) p[tid] = val;
}

__global__ void fill_f32(float* p, int n, float val) {
    int tid = blockIdx.x * blockDim.x + threadIdx.x;
    if (tid < n) p[tid] = val;
}

__global__ void copy_i32(int* dst, const int* src, int n) {
    int tid = blockIdx.x * blockDim.x + threadIdx.x;
    if (tid < n) dst[tid] = src[tid];
}

// convert fp32 -> bf16, vectorized (n multiple of 4)
__global__ void conv_bf16(const float* __restrict__ in, bf16s* __restrict__ out, int n4) {
    int tid = blockIdx.x * blockDim.x + threadIdx.x;
    if (tid >= n4) return;
    float4 v = reinterpret_cast<const float4*>(in)[tid];
    bf16x4 o;
    o[0] = f2bs(v.x); o[1] = f2bs(v.y); o[2] = f2bs(v.z); o[3] = f2bs(v.w);
    reinterpret_cast<bf16x4*>(out)[tid] = o;
}

// transpose W [K][256] fp32 -> Wt [256][K] bf16
__global__ void transpose_w(const float* __restrict__ W, bf16s* __restrict__ Wt, int K) {
    int tid = blockIdx.x * blockDim.x + threadIdx.x;
    if (tid >= K * HC) return;
    int c = tid / K, k = tid - c * K;
    Wt[tid] = f2bs(W[(size_t)k * HC + c]);
}

// ---------------- CSR build ----------------

__global__ void count_deg(const int* __restrict__ ei_dst, int* deg, int E) {
    int tid = blockIdx.x * blockDim.x + threadIdx.x;
    if (tid < E) atomicAdd(&deg[ei_dst[tid]], 1);
}

__global__ void scan_deg(const int* __restrict__ deg, int* __restrict__ rowptr, int n) {
    __shared__ int sdata[1024];
    __shared__ int carry;
    if (threadIdx.x == 0) { carry = 0; rowptr[0] = 0; }
    __syncthreads();
    for (int base = 0; base < n; base += 1024) {
        int i = base + threadIdx.x;
        int v = (i < n) ? deg[i] : 0;
        sdata[threadIdx.x] = v;
        __syncthreads();
        for (int off = 1; off < 1024; off <<= 1) {
            int t = (threadIdx.x >= off) ? sdata[threadIdx.x - off] : 0;
            __syncthreads();
            sdata[threadIdx.x] += t;
            __syncthreads();
        }
        int inc = sdata[threadIdx.x] + carry;
        if (i < n) rowptr[i + 1] = inc;
        __syncthreads();
        if (threadIdx.x == 1023) carry = inc;
        __syncthreads();
    }
}

__global__ void fill_csr(const int* __restrict__ ei, int* cursor, int* esrc, int E, int n) {
    int tid = blockIdx.x * blockDim.x + threadIdx.x;
    if (tid < E) {
        int src = ei[tid];
        int dst = ei[E + tid];
        int pos = atomicAdd(&cursor[dst], 1);
        esrc[pos] = src;
    } else if (tid < E + n) {
        int node = tid - E;
        int pos = atomicAdd(&cursor[node], 1);
        esrc[pos] = node;
    }
}

// ---------------- bf16 MFMA GEMM: H[M,256] = A[M,K] @ B[K,256] ----------------
// A: bf16 [M][K];  Wt: bf16 [256][K] (= B^T);  Hout: bf16 [M][256]
// tile 128x64, 4 waves, BK=64

__global__ __launch_bounds__(256) void gemm_bf16(
        const bf16s* __restrict__ A, const bf16s* __restrict__ Wt,
        bf16s* __restrict__ Hout, int M, int K) {
    __shared__ bf16s As[128][72];
    __shared__ bf16s Bs[64][72];
    int tid = threadIdx.x;
    int wave = tid >> 6, lane = tid & 63;
    int row0 = blockIdx.x * 128;
    int col0 = blockIdx.y * 64;
    int lr = lane & 15, lk = lane >> 4;

    f32x4 acc[2][4];
    #pragma unroll
    for (int i = 0; i < 2; i++)
        #pragma unroll
        for (int j = 0; j < 4; j++)
            acc[i][j] = (f32x4){0.f, 0.f, 0.f, 0.f};

    for (int k0 = 0; k0 < K; k0 += 64) {
        #pragma unroll
        for (int i = 0; i < 4; i++) {
            int idx = tid + i * 256;        // 1024 chunks of 16B
            int r = idx >> 3, ch = idx & 7;
            int gr = row0 + r;
            bf16x8 v = {};
            if (gr < M) v = *reinterpret_cast<const bf16x8*>(A + (size_t)gr * K + k0 + ch * 8);
            *reinterpret_cast<bf16x8*>(&As[r][ch * 8]) = v;
        }
        #pragma unroll
        for (int i = 0; i < 2; i++) {
            int idx = tid + i * 256;        // 512 chunks
            int r = idx >> 3, ch = idx & 7;
            bf16x8 v = *reinterpret_cast<const bf16x8*>(Wt + (size_t)(col0 + r) * K + k0 + ch * 8);
            *reinterpret_cast<bf16x8*>(&Bs[r][ch * 8]) = v;
        }
        __syncthreads();
        #pragma unroll
        for (int ks = 0; ks < 2; ks++) {
            bf16x8 bfr[4];
            #pragma unroll
            for (int j = 0; j < 4; j++)
                bfr[j] = *reinterpret_cast<const bf16x8*>(&Bs[j * 16 + lr][ks * 32 + lk * 8]);
            #pragma unroll
            for (int i = 0; i < 2; i++) {
                bf16x8 afr = *reinterpret_cast<const bf16x8*>(&As[wave * 32 + i * 16 + lr][ks * 32 + lk * 8]);
                #pragma unroll
                for (int j = 0; j < 4; j++)
                    acc[i][j] = __builtin_amdgcn_mfma_f32_16x16x32_bf16(afr, bfr[j], acc[i][j], 0, 0, 0);
            }
        }
        __syncthreads();
    }
    // C/D layout: col = lane&15, row = (lane>>4)*4 + q
    #pragma unroll
    for (int i = 0; i < 2; i++) {
        #pragma unroll
        for (int q = 0; q < 4; q++) {
            int r = row0 + wave * 32 + i * 16 + lk * 4 + q;
            if (r < M) {
                #pragma unroll
                for (int j = 0; j < 4; j++) {
                    int c = col0 + j * 16 + lr;
                    Hout[(size_t)r * HC + c] = f2bs(acc[i][j][q]);
                }
            }
        }
    }
}

// ---------------- attention coefficients: as/ad [N,H] ----------------

__global__ void attn_coef(const bf16s* __restrict__ hfeat,
                          const float* __restrict__ a_src, const float* __restrict__ a_dst,
                          float* __restrict__ asb, float* __restrict__ adb, int n) {
    int wave = blockIdx.x * (blockDim.x >> 6) + (threadIdx.x >> 6);
    int lane = threadIdx.x & 63;
    if (wave >= n) return;
    int h = lane >> 4;
    int c4 = (lane & 15) * 4;
    const bf16x4 hv = *reinterpret_cast<const bf16x4*>(hfeat + (size_t)wave * HC + h * HID + c4);
    const float4 sv = *reinterpret_cast<const float4*>(a_src + h * HID + c4);
    const float4 dv = *reinterpret_cast<const float4*>(a_dst + h * HID + c4);
    float h0 = bs2f(hv[0]), h1 = bs2f(hv[1]), h2 = bs2f(hv[2]), h3 = bs2f(hv[3]);
    float s = h0 * sv.x + h1 * sv.y + h2 * sv.z + h3 * sv.w;
    float d = h0 * dv.x + h1 * dv.y + h2 * dv.z + h3 * dv.w;
    #pragma unroll
    for (int off = 8; off > 0; off >>= 1) {
        s += __shfl_xor(s, off);
        d += __shfl_xor(d, off);
    }
    if ((lane & 15) == 0) {
        asb[wave * HEADS + h] = s;
        adb[wave * HEADS + h] = d;
    }
}

// ---------------- GAT aggregation: wave per destination node ----------------

__device__ __forceinline__ float lrelu(float x) { return x > 0.f ? x : NEG_SLOPE * x; }

__global__ __launch_bounds__(256) void gat_aggregate(
        const bf16s* __restrict__ hfeat,
        const float* __restrict__ asb, const float* __restrict__ adb,
        const int* __restrict__ rowptr, const int* __restrict__ esrc,
        const float* __restrict__ bias,  // [HC] or nullptr
        float* __restrict__ out) {       // [N,HC] fp32
    int d = blockIdx.x * (blockDim.x >> 6) + (threadIdx.x >> 6);
    int lane = threadIdx.x & 63;
    if (d >= N_NODES) return;
    int start = rowptr[d], end = rowptr[d + 1];

    float adv0 = adb[d * HEADS + 0], adv1 = adb[d * HEADS + 1];
    float adv2 = adb[d * HEADS + 2], adv3 = adb[d * HEADS + 3];

    // pass 1: per-head max
    float m0 = -1e30f, m1 = -1e30f, m2 = -1e30f, m3 = -1e30f;
    for (int j = start + lane; j < end; j += 64) {
        int s = esrc[j];
        const float4 av = *reinterpret_cast<const float4*>(asb + (size_t)s * HEADS);
        m0 = fmaxf(m0, lrelu(av.x + adv0));
        m1 = fmaxf(m1, lrelu(av.y + adv1));
        m2 = fmaxf(m2, lrelu(av.z + adv2));
        m3 = fmaxf(m3, lrelu(av.w + adv3));
    }
    #pragma unroll
    for (int off = 32; off > 0; off >>= 1) {
        m0 = fmaxf(m0, __shfl_xor(m0, off));
        m1 = fmaxf(m1, __shfl_xor(m1, off));
        m2 = fmaxf(m2, __shfl_xor(m2, off));
        m3 = fmaxf(m3, __shfl_xor(m3, off));
    }

    // pass 2: per-head sum of exp(e - m)
    float s0 = 0.f, s1 = 0.f, s2 = 0.f, s3 = 0.f;
    for (int j = start + lane; j < end; j += 64) {
        int s = esrc[j];
        const float4 av = *reinterpret_cast<const float4*>(asb + (size_t)s * HEADS);
        s0 += __expf(lrelu(av.x + adv0) - m0);
        s1 += __expf(lrelu(av.y + adv1) - m1);
        s2 += __expf(lrelu(av.z + adv2) - m2);
        s3 += __expf(lrelu(av.w + adv3) - m3);
    }
    #pragma unroll
    for (int off = 32; off > 0; off >>= 1) {
        s0 += __shfl_xor(s0, off);
        s1 += __shfl_xor(s1, off);
        s2 += __shfl_xor(s2, off);
        s3 += __shfl_xor(s3, off);
    }
    float r0 = 1.f / (s0 + 1e-16f), r1 = 1.f / (s1 + 1e-16f);
    float r2 = 1.f / (s2 + 1e-16f), r3 = 1.f / (s3 + 1e-16f);

    // pass 3: 2 edges per iteration; lanes 0-31 edge j, lanes 32-63 edge j+1.
    // lane covers cols cl*8 .. cl*8+7 (bf16x8 = 16B load)
    int half = lane >> 5;
    int cl = lane & 31;
    int hsel = cl >> 3;
    float mh  = (hsel == 0) ? m0 : (hsel == 1) ? m1 : (hsel == 2) ? m2 : m3;
    float rdh = (hsel == 0) ? r0 : (hsel == 1) ? r1 : (hsel == 2) ? r2 : r3;
    float adh = (hsel == 0) ? adv0 : (hsel == 1) ? adv1 : (hsel == 2) ? adv2 : adv3;

    float av0 = 0.f, av1 = 0.f, av2 = 0.f, av3 = 0.f;
    float av4 = 0.f, av5 = 0.f, av6 = 0.f, av7 = 0.f;
    for (int j = start; j < end; j += 2) {
        int jj = j + half;
        if (jj < end) {
            int s = esrc[jj];
            float e = lrelu(asb[(size_t)s * HEADS + hsel] + adh);
            float alpha = __expf(e - mh) * rdh;
            const bf16x8 v = *reinterpret_cast<const bf16x8*>(hfeat + (size_t)s * HC + cl * 8);
            av0 += alpha * bs2f(v[0]); av1 += alpha * bs2f(v[1]);
            av2 += alpha * bs2f(v[2]); av3 += alpha * bs2f(v[3]);
            av4 += alpha * bs2f(v[4]); av5 += alpha * bs2f(v[5]);
            av6 += alpha * bs2f(v[6]); av7 += alpha * bs2f(v[7]);
        }
    }
    // combine the two halves (same cols, disjoint edge subsets)
    av0 += __shfl_xor(av0, 32); av1 += __shfl_xor(av1, 32);
    av2 += __shfl_xor(av2, 32); av3 += __shfl_xor(av3, 32);
    av4 += __shfl_xor(av4, 32); av5 += __shfl_xor(av5, 32);
    av6 += __shfl_xor(av6, 32); av7 += __shfl_xor(av7, 32);

    if (half == 0) {
        if (bias) {
            const float4 b0 = *reinterpret_cast<const float4*>(bias + cl * 8);
            const float4 b1 = *reinterpret_cast<const float4*>(bias + cl * 8 + 4);
            av0 += b0.x; av1 += b0.y; av2 += b0.z; av3 += b0.w;
            av4 += b1.x; av5 += b1.y; av6 += b1.z; av7 += b1.w;
        }
        float4 o0; o0.x = av0; o0.y = av1; o0.z = av2; o0.w = av3;
        float4 o1; o1.x = av4; o1.y = av5; o1.z = av6; o1.w = av7;
        *reinterpret_cast<float4*>(out + (size_t)d * HC + cl * 8) = o0;
        *reinterpret_cast<float4*>(out + (size_t)d * HC + cl * 8 + 4) = o1;
    }
}

// ---------------- BatchNorm ----------------

__global__ void bn_stats(const float* __restrict__ x, float* colsum, float* colsq, int n) {
    int col = threadIdx.x;  // 256 threads
    float s = 0.f, q = 0.f;
    for (int r = blockIdx.x; r < n; r += gridDim.x) {
        float v = x[(size_t)r * HC + col];
        s += v;
        q += v * v;
    }
    atomicAdd(&colsum[col], s);
    atomicAdd(&colsq[col], q);
}

__global__ void bn_finalize(const float* colsum, const float* colsq,
                            const float* __restrict__ g, const float* __restrict__ be,
                            float* scale, float* shift, int n) {
    int col = threadIdx.x;  // 256
    float mu = colsum[col] / (float)n;
    float var = colsq[col] / (float)n - mu * mu;
    float sc = g[col] * rsqrtf(var + BN_EPS);
    scale[col] = sc;
    shift[col] = be[col] - mu * sc;
}

// writes xs (fp32, graded output) and act (bf16, next-layer GEMM input)
__global__ void bn_apply_elu(const float* __restrict__ x,
                             const float* __restrict__ scale, const float* __restrict__ shift,
                             float* __restrict__ xs_out, bf16s* __restrict__ act, int n) {
    int col = threadIdx.x;  // 256
    float sc = scale[col], sh = shift[col];
    for (int r = blockIdx.x; r < n; r += gridDim.x) {
        float v = x[(size_t)r * HC + col];
        float y = v * sc + sh;
        xs_out[(size_t)r * HC + col] = y;
        float e = y > 0.f ? y : __expf(y) - 1.f;
        act[(size_t)r * HC + col] = f2bs(e);
    }
}

// ---------------- layer-3 head mean, pool, final linear ----------------

__global__ void head_mean(const float* __restrict__ gatout, const float* __restrict__ b3,
                          float* __restrict__ xs2, int n) {
    int tid = blockIdx.x * blockDim.x + threadIdx.x;
    if (tid >= n * HID) return;
    int node = tid >> 6, c = tid & 63;
    const float* row = gatout + (size_t)node * HC;
    float v = 0.25f * (row[c] + row[HID + c] + row[2 * HID + c] + row[3 * HID + c]) + b3[c];
    xs2[tid] = v;
}

__global__ void pool_accum(const float* __restrict__ xs2, const int* __restrict__ batch,
                           float* pool, float* cnt, int n) {
    int tid = blockIdx.x * blockDim.x + threadIdx.x;
    if (tid >= n * HID) return;
    int node = tid >> 6, c = tid & 63;
    int g = batch[node];
    atomicAdd(&pool[g * HID + c], xs2[tid]);
    if (c == 0) atomicAdd(&cnt[g], 1.0f);
}

__global__ void pool_fin(const float* pool, const float* cnt, float* pooled_out) {
    int tid = blockIdx.x * blockDim.x + threadIdx.x;
    if (tid >= NUM_GRAPHS * HID) return;
    int g = tid >> 6;
    pooled_out[tid] = pool[tid] / fmaxf(cnt[g], 1.0f);
}

__global__ void final_linear(const float* __restrict__ pooled, const float* __restrict__ Wlin,
                             const float* __restrict__ blin, float* __restrict__ out) {
    int tid = blockIdx.x * blockDim.x + threadIdx.x;
    if (tid >= NUM_GRAPHS * OUT_DIM) return;
    int g = tid / OUT_DIM, o = tid % OUT_DIM;
    float s = blin[o];
    for (int c = 0; c < HID; ++c) s += pooled[g * HID + c] * Wlin[c * OUT_DIM + o];
    out[g * OUT_DIM + o] = s;
}

// ---------------- host side ----------------

extern "C" void kernel_launch(void* const* d_in, const int* in_sizes, int n_in,
                              void* d_out, int out_size, void* d_ws, size_t ws_size,
                              hipStream_t stream) {
    const float* x     = (const float*)d_in[0];
    const int*   ei    = (const int*)d_in[1];   // [2,E]
    const int*   batch = (const int*)d_in[2];
    const float* W1  = (const float*)d_in[3];
    const float* as1 = (const float*)d_in[4];
    const float* ad1 = (const float*)d_in[5];
    const float* b1  = (const float*)d_in[6];
    const float* g1  = (const float*)d_in[7];
    const float* be1 = (const float*)d_in[8];
    const float* W2  = (const float*)d_in[9];
    const float* as2 = (const float*)d_in[10];
    const float* ad2 = (const float*)d_in[11];
    const float* b2  = (const float*)d_in[12];
    const float* g2  = (const float*)d_in[13];
    const float* be2 = (const float*)d_in[14];
    const float* W3  = (const float*)d_in[15];
    const float* as3 = (const float*)d_in[16];
    const float* ad3 = (const float*)d_in[17];
    const float* b3  = (const float*)d_in[18];
    const float* Wlin = (const float*)d_in[19];
    const float* blin = (const float*)d_in[20];

    // output regions
    float* out_final = (float*)d_out;                 // [128,10]
    float* xs0 = out_final + NUM_GRAPHS * OUT_DIM;    // [N,256]
    float* xs1 = xs0 + (size_t)N_NODES * HC;          // [N,256]
    float* xs2 = xs1 + (size_t)N_NODES * HC;          // [N,64]
    float* pooled_out = xs2 + (size_t)N_NODES * HID;  // [128,64]

    // workspace carve
    char* p = (char*)d_ws;
    auto alloc = [&](size_t bytes) { char* r = p; p += (bytes + 255) & ~(size_t)255; return (void*)r; };
    bf16s* hfeat  = (bf16s*)alloc((size_t)N_NODES * HC * 2);     // bf16 h
    bf16s* actC   = (bf16s*)alloc((size_t)N_NODES * HC * 2);     // bf16 activations
    bf16s* xb     = (bf16s*)alloc((size_t)N_NODES * F_IN * 2);   // bf16 input x
    float* gatB   = (float*)alloc((size_t)N_NODES * HC * 4);     // fp32 GAT output
    bf16s* Wt1    = (bf16s*)alloc((size_t)HC * F_IN * 2);
    bf16s* Wt2    = (bf16s*)alloc((size_t)HC * HC * 2);
    bf16s* Wt3    = (bf16s*)alloc((size_t)HC * HC * 2);
    float* asb    = (float*)alloc((size_t)N_NODES * HEADS * 4);
    float* adb    = (float*)alloc((size_t)N_NODES * HEADS * 4);
    int*   deg    = (int*)alloc((size_t)N_NODES * 4);     // reused as cursor
    int*   rowptr = (int*)alloc((size_t)(N_NODES + 1) * 4);
    int*   esrc   = (int*)alloc((size_t)(N_EDGES + N_NODES) * 4);
    float* colstats = (float*)alloc(2 * HC * 4);          // colsum | colsq
    float* colsum = colstats;
    float* colsq  = colstats + HC;
    float* scale  = (float*)alloc(HC * 4);
    float* shift  = (float*)alloc(HC * 4);
    float* poolbuf = (float*)alloc((NUM_GRAPHS * HID + NUM_GRAPHS) * 4);  // pool | cnt
    float* pool   = poolbuf;
    float* cnt    = poolbuf + NUM_GRAPHS * HID;

    const int ETOT = N_EDGES + N_NODES;

    // ---- CSR build (once, reused for all 3 layers) ----
    fill_i32<<<(N_NODES + 255) / 256, 256, 0, stream>>>(deg, N_NODES, 1);  // self-loop
    count_deg<<<(N_EDGES + 255) / 256, 256, 0, stream>>>(ei + N_EDGES, deg, N_EDGES);
    scan_deg<<<1, 1024, 0, stream>>>(deg, rowptr, N_NODES);
    copy_i32<<<(N_NODES + 255) / 256, 256, 0, stream>>>(deg, rowptr, N_NODES);  // deg -> cursor
    fill_csr<<<(ETOT + 255) / 256, 256, 0, stream>>>(ei, deg, esrc, N_EDGES, N_NODES);

    // ---- weight prep ----
    conv_bf16<<<((N_NODES * F_IN / 4) + 255) / 256, 256, 0, stream>>>(x, xb, N_NODES * F_IN / 4);
    transpose_w<<<(HC * F_IN + 255) / 256, 256, 0, stream>>>(W1, Wt1, F_IN);
    transpose_w<<<(HC * HC + 255) / 256, 256, 0, stream>>>(W2, Wt2, HC);
    transpose_w<<<(HC * HC + 255) / 256, 256, 0, stream>>>(W3, Wt3, HC);

    int wave_blocks = (N_NODES + 3) / 4;  // 4 waves per 256-thread block
    dim3 ggrid((N_NODES + 127) / 128, HC / 64);

    // ---- layer 1 ----
    {
        gemm_bf16<<<ggrid, 256, 0, stream>>>(xb, Wt1, hfeat, N_NODES, F_IN);
        attn_coef<<<wave_blocks, 256, 0, stream>>>(hfeat, as1, ad1, asb, adb, N_NODES);
        gat_aggregate<<<wave_blocks, 256, 0, stream>>>(hfeat, asb, adb, rowptr, esrc, b1, gatB);
        fill_f32<<<2, 256, 0, stream>>>(colstats, 2 * HC, 0.f);
        bn_stats<<<512, 256, 0, stream>>>(gatB, colsum, colsq, N_NODES);
        bn_finalize<<<1, 256, 0, stream>>>(colsum, colsq, g1, be1, scale, shift, N_NODES);
        bn_apply_elu<<<2048, 256, 0, stream>>>(gatB, scale, shift, xs0, actC, N_NODES);
    }
    // ---- layer 2 ----
    {
        gemm_bf16<<<ggrid, 256, 0, stream>>>(actC, Wt2, hfeat, N_NODES, HC);
        attn_coef<<<wave_blocks, 256, 0, stream>>>(hfeat, as2, ad2, asb, adb, N_NODES);
        gat_aggregate<<<wave_blocks, 256, 0, stream>>>(hfeat, asb, adb, rowptr, esrc, b2, gatB);
        fill_f32<<<2, 256, 0, stream>>>(colstats, 2 * HC, 0.f);
        bn_stats<<<512, 256, 0, stream>>>(gatB, colsum, colsq, N_NODES);
        bn_finalize<<<1, 256, 0, stream>>>(colsum, colsq, g2, be2, scale, shift, N_NODES);
        bn_apply_elu<<<2048, 256, 0, stream>>>(gatB, scale, shift, xs1, actC, N_NODES);
    }
    // ---- layer 3 ----
    {
        gemm_bf16<<<ggrid, 256, 0, stream>>>(actC, Wt3, hfeat, N_NODES, HC);
        attn_coef<<<wave_blocks, 256, 0, stream>>>(hfeat, as3, ad3, asb, adb, N_NODES);
        gat_aggregate<<<wave_blocks, 256, 0, stream>>>(hfeat, asb, adb, rowptr, esrc, nullptr, gatB);
        head_mean<<<((N_NODES * HID) + 255) / 256, 256, 0, stream>>>(gatB, b3, xs2, N_NODES);
    }
    // ---- pool + final linear ----
    fill_f32<<<(NUM_GRAPHS * HID + NUM_GRAPHS + 255) / 256, 256, 0, stream>>>(poolbuf, NUM_GRAPHS * HID + NUM_GRAPHS, 0.f);
    pool_accum<<<((N_NODES * HID) + 255) / 256, 256, 0, stream>>>(xs2, batch, pool, cnt, N_NODES);
    pool_fin<<<(NUM_GRAPHS * HID + 255) / 256, 256, 0, stream>>>(pool, cnt, pooled_out);
    final_linear<<<(NUM_GRAPHS * OUT_DIM + 255) / 256, 256, 0, stream>>>(pooled_out, Wlin, blin, out_final);
}